// Round 17
// baseline (125.522 us; speedup 1.0000x reference)
//
#include <hip/hip_runtime.h>
#include <math.h>

// FrequencyAttention: QF = (TWF.qT).W^T ; d_out = TWI.(U.OVW^T)^T + b_out.
// Split-bf16 MFMA (hi/lo, 3-term) on 64x64 tiles. R17: 6 launches.
// Split-K partials are consumed by the NEXT GEMM's staging (4-slice sum +
// split, reg->LDS, off the fragment path) -- no reduce kernels, no TWQ/POV.
//   prep -> A(KS=4 -> P_A) -> B(A from P_A, w fp32; KS=2 -> P_B)
//        -> score_ov(P_B -> attn(LDS) -> OVW bf16) -> C(KS=4 -> P_C)
//        -> D(B from P_C -> d_out).

#define PB_STRIDE 2097152   // floats per P_B slice (2^21)
#define PA_SLICE  131072    // floats per P_A / P_C slice

typedef __bf16 bf16x8 __attribute__((ext_vector_type(8)));
typedef float  f32x4  __attribute__((ext_vector_type(4)));

__device__ __forceinline__ unsigned short f2bf(float x) {
    unsigned u = __builtin_bit_cast(unsigned, x);
    u = (u + 0x7fffu + ((u >> 16) & 1u)) >> 16;   // RTN-even
    return (unsigned short)u;
}
__device__ __forceinline__ float bf2f(unsigned short h) {
    return __builtin_bit_cast(float, ((unsigned)h) << 16);
}
__device__ __forceinline__ void split2(float x, unsigned short& h, unsigned short& l) {
    h = f2bf(x);
    l = f2bf(x - bf2f(h));
}
__device__ __forceinline__ float4 add4(float4 a, float4 b) {
    float4 r; r.x = a.x + b.x; r.y = a.y + b.y; r.z = a.z + b.z; r.w = a.w + b.w;
    return r;
}
// split 8 fp32 -> bf16 hi/lo, store 16B each to LDS
__device__ __forceinline__ void splitst(const float4& a0, const float4& a1,
                                        unsigned short* dsth, unsigned short* dstl) {
    float v[8] = {a0.x, a0.y, a0.z, a0.w, a1.x, a1.y, a1.z, a1.w};
    bf16x8 hv, lv;
#pragma unroll
    for (int j = 0; j < 8; j++) {
        unsigned short h, l; split2(v[j], h, l);
        hv[j] = __builtin_bit_cast(__bf16, h);
        lv[j] = __builtin_bit_cast(__bf16, l);
    }
    *reinterpret_cast<bf16x8*>(dsth) = hv;
    *reinterpret_cast<bf16x8*>(dstl) = lv;
}
// sum of 4 fp32 slices (stride PA_SLICE), 8 elems
__device__ __forceinline__ void sum4(const float* p, float4& o0, float4& o1) {
    float4 x0 = *(const float4*)p,                  x1 = *(const float4*)(p + 4);
    float4 y0 = *(const float4*)(p + PA_SLICE),     y1 = *(const float4*)(p + PA_SLICE + 4);
    float4 z0 = *(const float4*)(p + 2 * PA_SLICE), z1 = *(const float4*)(p + 2 * PA_SLICE + 4);
    float4 w0 = *(const float4*)(p + 3 * PA_SLICE), w1 = *(const float4*)(p + 3 * PA_SLICE + 4);
    o0 = add4(add4(x0, y0), add4(z0, w0));
    o1 = add4(add4(x1, y1), add4(z1, w1));
}

__device__ __forceinline__ void gload16(const void* g, void* l) {
    __builtin_amdgcn_global_load_lds(
        (const __attribute__((address_space(1))) unsigned int*)g,
        (__attribute__((address_space(3))) unsigned int*)l,
        16, 0, 0);
}

// ---- prep: twiddles + query transpose/split ---------------------------------
__global__ __launch_bounds__(256) void prep(
    const float* __restrict__ q,
    unsigned short* __restrict__ qTh, unsigned short* __restrict__ qTl,
    unsigned short* __restrict__ TWFh, unsigned short* __restrict__ TWFl,
    unsigned short* __restrict__ TWIh, unsigned short* __restrict__ TWIl)
{
    __shared__ float T[64][65];
    int bid = blockIdx.x, tid = threadIdx.x;
    if (bid < 256) {                       // twiddles: 65536 = 64f x 1024s
        int idx = bid * 256 + tid;
        int f = idx >> 10, s = idx & 1023;
        float th = (float)((f * s) & 1023) * (6.283185307179586f / 1024.0f);
        float sn, c;
        sincosf(th, &sn, &c);
        unsigned short ch, cl, sh, sl;
        split2(c, ch, cl); split2(sn, sh, sl);
        TWFh[(2 * f) * 1024 + s] = ch;     TWFl[(2 * f) * 1024 + s] = cl;
        TWFh[(2 * f + 1) * 1024 + s] = sh; TWFl[(2 * f + 1) * 1024 + s] = sl;
        TWIh[s * 128 + 2 * f] = ch;        TWIl[s * 128 + 2 * f] = cl;
        TWIh[s * 128 + 2 * f + 1] = sh;    TWIl[s * 128 + 2 * f + 1] = sl;
    } else {                               // transpose+split query, 1024 blocks
        int t = bid - 256;
        int k0 = (t & 15) * 64, s0 = ((t >> 4) & 15) * 64, b = t >> 8;
        const float* src = q + ((size_t)b * 1024 + s0) * 1024 + k0;
        int tr = tid >> 4, tc4 = (tid & 15) * 4;
#pragma unroll
        for (int rs = 0; rs < 4; rs++) {
            int r = rs * 16 + tr;
            float4 v = *(const float4*)&src[(size_t)r * 1024 + tc4];
            T[tc4 + 0][r] = v.x; T[tc4 + 1][r] = v.y;
            T[tc4 + 2][r] = v.z; T[tc4 + 3][r] = v.w;
        }
        __syncthreads();
        unsigned short* dh = qTh + ((size_t)b * 1024 + k0) * 1024 + s0;
        unsigned short* dl = qTl + ((size_t)b * 1024 + k0) * 1024 + s0;
#pragma unroll
        for (int rs = 0; rs < 4; rs++) {
            int kk = rs * 16 + tr;
            ushort4 hh, ll;
            split2(T[kk][tc4 + 0], hh.x, ll.x);
            split2(T[kk][tc4 + 1], hh.y, ll.y);
            split2(T[kk][tc4 + 2], hh.z, ll.z);
            split2(T[kk][tc4 + 3], hh.w, ll.w);
            *(ushort4*)&dh[(size_t)kk * 1024 + tc4] = hh;
            *(ushort4*)&dl[(size_t)kk * 1024 + tc4] = ll;
        }
    }
}

// ---- 64x64-tile split-bf16 MFMA NT GEMM, dbuf LDS ---------------------------
// AM/BM: 0 = bf16 hi/lo gload, 1 = fp32 staged-split,
//        2 = 4-slice fp32 partial sum staged-split (A: rows are (b,f2), slices
//            at Af32+(b*4+s)*PA_SLICE; B: rows local, slices at
//            Bf32+(bz*4+s)*PA_SLICE).
// KS>1: fp32 partial at Pf + z*bsC. BMODE: 0 none, 1 col-bias, 2 DC-row bias
// (+1024*b[n] where (row&127)==0; partials: only at ks==0).
template<int KS, int BMODE, int AM, int BM>
__global__ __launch_bounds__(256, 4) void mfma64(
    const unsigned short* __restrict__ Ah, const unsigned short* __restrict__ Al,
    const float* __restrict__ Af32, int lda, long bsA,
    const unsigned short* __restrict__ Bh, const unsigned short* __restrict__ Bl,
    const float* __restrict__ Bf32, int ldb, long bsB,
    float* __restrict__ Cf, int ldc, long bsC,
    float* __restrict__ Pf, const float* __restrict__ bias, int K)
{
    __shared__ unsigned short smem[2][8192];
    const int tid = threadIdx.x, lane = tid & 63, w = tid >> 6;
    const int wm = w >> 1, wn = w & 1;
    const int m0 = blockIdx.y * 64, n0 = blockIdx.x * 64;
    const int la = lane & 15, kg = lane >> 4;
    int bz, ks;
    if constexpr (KS > 1) { bz = blockIdx.z / KS; ks = blockIdx.z % KS; }
    else                  { bz = blockIdx.z; ks = 0; }
    const int Kc = K / KS;

    const unsigned short *pAh = nullptr, *pAl = nullptr, *pBh = nullptr, *pBl = nullptr;
    const float *pA32 = nullptr, *pB32 = nullptr;
    if constexpr (AM == 0) {
        pAh = Ah + (long)bz * bsA + (size_t)(m0 + w * 16 + la) * lda + ks * Kc + kg * 8;
        pAl = Al + (long)bz * bsA + (size_t)(m0 + w * 16 + la) * lda + ks * Kc + kg * 8;
    } else if constexpr (AM == 1) {
        pA32 = Af32 + (long)bz * bsA + (size_t)(m0 + w * 16 + la) * lda + ks * Kc + kg * 8;
    } else {
        int rowA = m0 + w * 16 + la;             // (b,f2) flattened
        int bA = rowA >> 7, rlA = rowA & 127;
        pA32 = Af32 + (long)bA * (4L * PA_SLICE) + (size_t)rlA * lda + ks * Kc + kg * 8;
    }
    if constexpr (BM == 0) {
        pBh = Bh + (long)bz * bsB + (size_t)(n0 + w * 16 + la) * ldb + ks * Kc + kg * 8;
        pBl = Bl + (long)bz * bsB + (size_t)(n0 + w * 16 + la) * ldb + ks * Kc + kg * 8;
    } else if constexpr (BM == 1) {
        pB32 = Bf32 + (long)bz * bsB + (size_t)(n0 + w * 16 + la) * ldb + ks * Kc + kg * 8;
    } else {
        pB32 = Bf32 + (long)bz * (4L * PA_SLICE) + (size_t)(n0 + w * 16 + la) * ldb + ks * Kc + kg * 8;
    }

    // prologue: stage tile 0 into buffer 0
    if constexpr (AM == 0) {
        gload16(pAh, &smem[0][w * 512]); gload16(pAl, &smem[0][2048 + w * 512]);
        pAh += 32; pAl += 32;
    } else if constexpr (AM == 1) {
        float4 a0 = *(const float4*)pA32, a1 = *(const float4*)(pA32 + 4); pA32 += 32;
        splitst(a0, a1, &smem[0][w * 512 + lane * 8], &smem[0][2048 + w * 512 + lane * 8]);
    } else {
        float4 a0, a1; sum4(pA32, a0, a1); pA32 += 32;
        splitst(a0, a1, &smem[0][w * 512 + lane * 8], &smem[0][2048 + w * 512 + lane * 8]);
    }
    if constexpr (BM == 0) {
        gload16(pBh, &smem[0][4096 + w * 512]); gload16(pBl, &smem[0][6144 + w * 512]);
        pBh += 32; pBl += 32;
    } else if constexpr (BM == 1) {
        float4 b0 = *(const float4*)pB32, b1 = *(const float4*)(pB32 + 4); pB32 += 32;
        splitst(b0, b1, &smem[0][4096 + w * 512 + lane * 8], &smem[0][6144 + w * 512 + lane * 8]);
    } else {
        float4 b0, b1; sum4(pB32, b0, b1); pB32 += 32;
        splitst(b0, b1, &smem[0][4096 + w * 512 + lane * 8], &smem[0][6144 + w * 512 + lane * 8]);
    }
    __syncthreads();

    f32x4 acc[2][2] = {};
    int cur = 0;
    for (int kt = 0; kt < Kc; kt += 32) {
        const bool hn = (kt + 32 < Kc);
        float4 na0, na1, nb0, nb1;
        if (hn) {                          // issue next-tile loads BEFORE compute
            int nb = cur ^ 1;
            if constexpr (AM == 0) {
                gload16(pAh, &smem[nb][w * 512]); gload16(pAl, &smem[nb][2048 + w * 512]);
                pAh += 32; pAl += 32;
            } else if constexpr (AM == 1) {
                na0 = *(const float4*)pA32; na1 = *(const float4*)(pA32 + 4); pA32 += 32;
            } else {
                sum4(pA32, na0, na1); pA32 += 32;
            }
            if constexpr (BM == 0) {
                gload16(pBh, &smem[nb][4096 + w * 512]); gload16(pBl, &smem[nb][6144 + w * 512]);
                pBh += 32; pBl += 32;
            } else if constexpr (BM == 1) {
                nb0 = *(const float4*)pB32; nb1 = *(const float4*)(pB32 + 4); pB32 += 32;
            } else {
                sum4(pB32, nb0, nb1); pB32 += 32;
            }
        }
        bf16x8 fah[2], fal[2], fbh[2], fbl[2];
#pragma unroll
        for (int i = 0; i < 2; i++) {
            fah[i] = *reinterpret_cast<const bf16x8*>(&smem[cur][(wm * 2 + i) * 512 + lane * 8]);
            fal[i] = *reinterpret_cast<const bf16x8*>(&smem[cur][2048 + (wm * 2 + i) * 512 + lane * 8]);
            fbh[i] = *reinterpret_cast<const bf16x8*>(&smem[cur][4096 + (wn * 2 + i) * 512 + lane * 8]);
            fbl[i] = *reinterpret_cast<const bf16x8*>(&smem[cur][6144 + (wn * 2 + i) * 512 + lane * 8]);
        }
#pragma unroll
        for (int j = 0; j < 2; j++)
#pragma unroll
            for (int i = 0; i < 2; i++) {
                acc[i][j] = __builtin_amdgcn_mfma_f32_16x16x32_bf16(fah[i], fbh[j], acc[i][j], 0, 0, 0);
                acc[i][j] = __builtin_amdgcn_mfma_f32_16x16x32_bf16(fal[i], fbh[j], acc[i][j], 0, 0, 0);
                acc[i][j] = __builtin_amdgcn_mfma_f32_16x16x32_bf16(fah[i], fbl[j], acc[i][j], 0, 0, 0);
            }
        if (hn) {                          // split+write after compute, pre-barrier
            int nb = cur ^ 1;
            if constexpr (AM != 0)
                splitst(na0, na1, &smem[nb][w * 512 + lane * 8], &smem[nb][2048 + w * 512 + lane * 8]);
            if constexpr (BM != 0)
                splitst(nb0, nb1, &smem[nb][4096 + w * 512 + lane * 8], &smem[nb][6144 + w * 512 + lane * 8]);
        }
        __syncthreads();
        cur ^= 1;
    }

    const int r0_ = (lane >> 4) * 4, cl = lane & 15;
    if constexpr (KS > 1) {
        const int N = gridDim.x * 64;
        float* Pb = Pf + (long)blockIdx.z * bsC;
#pragma unroll
        for (int i = 0; i < 2; i++)
#pragma unroll
            for (int j = 0; j < 2; j++) {
                int gr0 = m0 + wm * 32 + i * 16 + r0_;
                int gc  = n0 + wn * 32 + j * 16 + cl;
#pragma unroll
                for (int r = 0; r < 4; r++) {
                    int gr = gr0 + r;
                    float v = acc[i][j][r];
                    if (BMODE == 2 && ks == 0 && (gr & 127) == 0)
                        v += 1024.0f * bias[gc];
                    Pb[(long)gr * N + gc] = v;
                }
            }
    } else {
        float* Cfb = Cf + (long)bz * bsC;
#pragma unroll
        for (int i = 0; i < 2; i++)
#pragma unroll
            for (int j = 0; j < 2; j++) {
                int gr0 = m0 + wm * 32 + i * 16 + r0_;
                int gc  = n0 + wn * 32 + j * 16 + cl;
                float bn = (BMODE == 1) ? bias[gc] : 0.f;
#pragma unroll
                for (int r = 0; r < 4; r++) {
                    int gr = gr0 + r;
                    float v = acc[i][j][r] + bn;
                    if (BMODE == 2 && (gr & 127) == 0) v += 1024.0f * bias[gc];
                    Cfb[(size_t)gr * ldc + gc] = v;
                }
            }
    }
}

// ---- fused scores + softmax + OVW: block per (b,h), reads P_B directly ------
__global__ __launch_bounds__(256) void score_ov(
    const float* __restrict__ P, const float* __restrict__ fq,
    const float* __restrict__ fk, const float* __restrict__ fv,
    unsigned short* __restrict__ OVWh, unsigned short* __restrict__ OVWl)
{
    int blk = blockIdx.x, tid = threadIdx.x;
    int b = blk >> 4, h = blk & 15;
    int f = tid & 63, part = tid >> 6;
    const float* base0 = P + (long)(b * 128 + 2 * f) * 3072 + h * 64 + part * 16;
    float acc = 0.f;
#pragma unroll
    for (int rr = 0; rr < 2; rr++) {
        const float* p0 = base0 + rr * 3072;
        const float* p1 = p0 + PB_STRIDE;
#pragma unroll
        for (int g = 0; g < 4; g++) {
            float4 a0 = *(const float4*)(p0 + g * 4);
            float4 a1 = *(const float4*)(p1 + g * 4);
            float4 k0 = *(const float4*)(p0 + 1024 + g * 4);
            float4 k1 = *(const float4*)(p1 + 1024 + g * 4);
            const float4 wq = *(const float4*)&fq[h * 4096 + f * 64 + part * 16 + g * 4];
            const float4 wk = *(const float4*)&fk[h * 4096 + f * 64 + part * 16 + g * 4];
            acc += wq.x * wk.x * (a0.x + a1.x) * (k0.x + k1.x)
                 + wq.y * wk.y * (a0.y + a1.y) * (k0.y + k1.y)
                 + wq.z * wk.z * (a0.z + a1.z) * (k0.z + k1.z)
                 + wq.w * wk.w * (a0.w + a1.w) * (k0.w + k1.w);
        }
    }
    __shared__ float red[256];
    __shared__ float attnL[64];
    red[tid] = acc;
    __syncthreads();
    if (tid < 64) {
        float s = red[tid] + red[tid + 64] + red[tid + 128] + red[tid + 192];
        float mx = s;
        for (int m = 1; m < 64; m <<= 1) mx = fmaxf(mx, __shfl_xor(mx, m));
        mx = fmaxf(mx, 0.0f);                   // padded zero scores join the max
        float e = expf(s - mx);
        float sum = e;
        for (int m = 1; m < 64; m <<= 1) sum += __shfl_xor(sum, m);
        sum += 960.0f * expf(-mx);              // the S-M zero-score entries
        attnL[tid] = e / sum;
    }
    __syncthreads();
    // phase 2: OVW[b][f2][h*64+d] = attn * wv * (P0+P1)v   (once-through)
#pragma unroll
    for (int it = 0; it < 8; it++) {
        int e = it * 256 + tid;                 // 2048 float4 units
        int f2 = e >> 4, c4 = e & 15;
        int d = c4 * 4;
        const float* p0 = P + (long)(b * 128 + f2) * 3072 + 2048 + h * 64 + d;
        float4 v0 = *(const float4*)p0;
        float4 v1 = *(const float4*)(p0 + PB_STRIDE);
        float a = attnL[f2 >> 1];
        const float4 wvv = *(const float4*)&fv[h * 4096 + (f2 >> 1) * 64 + d];
        ushort4 hh, ll;
        split2(a * wvv.x * (v0.x + v1.x), hh.x, ll.x);
        split2(a * wvv.y * (v0.y + v1.y), hh.y, ll.y);
        split2(a * wvv.z * (v0.z + v1.z), hh.z, ll.z);
        split2(a * wvv.w * (v0.w + v1.w), hh.w, ll.w);
        long o4 = ((long)(b * 128 + f2) * 1024 + h * 64 + d) >> 2;
        ((ushort4*)OVWh)[o4] = hh;
        ((ushort4*)OVWl)[o4] = ll;
    }
}

extern "C" void kernel_launch(void* const* d_in, const int* in_sizes, int n_in,
                              void* d_out, int out_size, void* d_ws, size_t ws_size,
                              hipStream_t stream) {
    const float* query  = (const float*)d_in[0];
    const float* w_qkv  = (const float*)d_in[1];
    const float* b_qkv  = (const float*)d_in[2];
    const float* w_out  = (const float*)d_in[3];
    const float* b_out  = (const float*)d_in[4];
    const float* freq_q = (const float*)d_in[5];
    const float* freq_k = (const float*)d_in[6];
    const float* freq_v = (const float*)d_in[7];

    char* W = (char*)d_ws;
    unsigned short* qTh   = (unsigned short*)(W);                 // [4][1024][1024]
    unsigned short* qTl   = (unsigned short*)(W + 8388608);
    unsigned short* TWFh  = (unsigned short*)(W + 16777216);      // [128][1024]
    unsigned short* TWFl  = (unsigned short*)(W + 17039360);
    unsigned short* TWIh  = (unsigned short*)(W + 17301504);      // [1024][128]
    unsigned short* TWIl  = (unsigned short*)(W + 17563648);
    unsigned short* OVWh  = (unsigned short*)(W + 17825792);      // [4][128][1024]
    unsigned short* OVWl  = (unsigned short*)(W + 18874368);
    float*          P_A   = (float*)        (W + 19922944);       // [16][PA_SLICE]
    float*          P_B   = (float*)        (W + 28311552);       // [2][PB_STRIDE]
    float*          P_C   = (float*)        (W + 45088768);       // [16][PA_SLICE]
                                                                  // end 53477376 B

    prep<<<1280, 256, 0, stream>>>(query, qTh, qTl, TWFh, TWFl, TWIh, TWIl);

    // A: TWQ-partials: P_A[b*4+ks][f2][k] = sum_{s in ks} TWF[f2][s]*qT[b][k][s]
    mfma64<4, 0, 0, 0><<<dim3(16, 2, 16), 256, 0, stream>>>(
        TWFh, TWFl, nullptr, 1024, 0, qTh, qTl, nullptr, 1024, 1048576,
        nullptr, 0, PA_SLICE, P_A, nullptr, 1024);

    // B: QF-partials[(b,f2)][c] = sum_k (sum4 P_A)*w_qkv[c][k]  (KS=2, A from
    //    P_A staged-sum, w fp32 staged; +1024*b_qkv at DC rows in ks==0)
    mfma64<2, 2, 2, 1><<<dim3(48, 8, 2), 256, 0, stream>>>(
        nullptr, nullptr, P_A, 1024, 0, nullptr, nullptr, w_qkv, 1024, 0,
        nullptr, 0, PB_STRIDE, P_B, b_qkv, 1024);

    // fused scores + softmax + OVW  (attn lives only in LDS)
    score_ov<<<64, 256, 0, stream>>>(P_B, freq_q, freq_k, freq_v, OVWh, OVWl);

    // C: POV-partials: P_C[b*4+ks][n][f2] = sum_{ch in ks} w_out[n][ch]*OVW[b][f2][ch]
    mfma64<4, 0, 1, 0><<<dim3(2, 16, 16), 256, 0, stream>>>(
        nullptr, nullptr, w_out, 1024, 0, OVWh, OVWl, nullptr, 1024, 131072,
        nullptr, 0, PA_SLICE, P_C, nullptr, 1024);

    // D: d_out[b][s][n] = sum_f2 TWI[s][f2]*(sum4 P_C)[n][f2] + b_out[n]
    mfma64<1, 1, 0, 2><<<dim3(16, 16, 4), 256, 0, stream>>>(
        TWIh, TWIl, nullptr, 128, 0, nullptr, nullptr, P_C, 128, 0,
        (float*)d_out, 1024, 1048576, nullptr, b_out, 128);
}

// Round 19
// 87.203 us; speedup vs baseline: 1.4394x; 1.4394x over previous
//
#include <hip/hip_runtime.h>
#include <math.h>

// FrequencyAttention: QF = (TWF.qT).W^T ; d_out = TWI.(U.OVW^T)^T + b_out.
// Split-bf16 MFMA (hi/lo, 3-term) on 64x64 tiles; split-K + fp32 reduce.
// R18 = R16 component set, score+softmax+OVW merged into one kernel. 8 launches.
// Lesson bank: staged-split fusion only when panel re-read multiplicity ~1;
// compact bf16 (reduce_k) before any high-multiplicity re-read.

#define PB_STRIDE 2097152   // floats per P_B slice (2^21)

typedef __bf16 bf16x8 __attribute__((ext_vector_type(8)));
typedef float  f32x4  __attribute__((ext_vector_type(4)));

__device__ __forceinline__ unsigned short f2bf(float x) {
    unsigned u = __builtin_bit_cast(unsigned, x);
    u = (u + 0x7fffu + ((u >> 16) & 1u)) >> 16;   // RTN-even
    return (unsigned short)u;
}
__device__ __forceinline__ float bf2f(unsigned short h) {
    return __builtin_bit_cast(float, ((unsigned)h) << 16);
}
__device__ __forceinline__ void split2(float x, unsigned short& h, unsigned short& l) {
    h = f2bf(x);
    l = f2bf(x - bf2f(h));
}
// split 8 fp32 -> bf16 hi/lo, store 16B each to LDS
__device__ __forceinline__ void splitst(const float4& a0, const float4& a1,
                                        unsigned short* dsth, unsigned short* dstl) {
    float v[8] = {a0.x, a0.y, a0.z, a0.w, a1.x, a1.y, a1.z, a1.w};
    bf16x8 hv, lv;
#pragma unroll
    for (int j = 0; j < 8; j++) {
        unsigned short h, l; split2(v[j], h, l);
        hv[j] = __builtin_bit_cast(__bf16, h);
        lv[j] = __builtin_bit_cast(__bf16, l);
    }
    *reinterpret_cast<bf16x8*>(dsth) = hv;
    *reinterpret_cast<bf16x8*>(dstl) = lv;
}

__device__ __forceinline__ void gload16(const void* g, void* l) {
    __builtin_amdgcn_global_load_lds(
        (const __attribute__((address_space(1))) unsigned int*)g,
        (__attribute__((address_space(3))) unsigned int*)l,
        16, 0, 0);
}

// ---- prep: twiddles + query transpose/split ---------------------------------
__global__ __launch_bounds__(256) void prep(
    const float* __restrict__ q,
    unsigned short* __restrict__ qTh, unsigned short* __restrict__ qTl,
    unsigned short* __restrict__ TWFh, unsigned short* __restrict__ TWFl,
    unsigned short* __restrict__ TWIh, unsigned short* __restrict__ TWIl)
{
    __shared__ float T[64][65];
    int bid = blockIdx.x, tid = threadIdx.x;
    if (bid < 256) {                       // twiddles: 65536 = 64f x 1024s
        int idx = bid * 256 + tid;
        int f = idx >> 10, s = idx & 1023;
        float th = (float)((f * s) & 1023) * (6.283185307179586f / 1024.0f);
        float sn, c;
        sincosf(th, &sn, &c);
        unsigned short ch, cl, sh, sl;
        split2(c, ch, cl); split2(sn, sh, sl);
        TWFh[(2 * f) * 1024 + s] = ch;     TWFl[(2 * f) * 1024 + s] = cl;
        TWFh[(2 * f + 1) * 1024 + s] = sh; TWFl[(2 * f + 1) * 1024 + s] = sl;
        TWIh[s * 128 + 2 * f] = ch;        TWIl[s * 128 + 2 * f] = cl;
        TWIh[s * 128 + 2 * f + 1] = sh;    TWIl[s * 128 + 2 * f + 1] = sl;
    } else {                               // transpose+split query, 1024 blocks
        int t = bid - 256;
        int k0 = (t & 15) * 64, s0 = ((t >> 4) & 15) * 64, b = t >> 8;
        const float* src = q + ((size_t)b * 1024 + s0) * 1024 + k0;
        int tr = tid >> 4, tc4 = (tid & 15) * 4;
#pragma unroll
        for (int rs = 0; rs < 4; rs++) {
            int r = rs * 16 + tr;
            float4 v = *(const float4*)&src[(size_t)r * 1024 + tc4];
            T[tc4 + 0][r] = v.x; T[tc4 + 1][r] = v.y;
            T[tc4 + 2][r] = v.z; T[tc4 + 3][r] = v.w;
        }
        __syncthreads();
        unsigned short* dh = qTh + ((size_t)b * 1024 + k0) * 1024 + s0;
        unsigned short* dl = qTl + ((size_t)b * 1024 + k0) * 1024 + s0;
#pragma unroll
        for (int rs = 0; rs < 4; rs++) {
            int kk = rs * 16 + tr;
            ushort4 hh, ll;
            split2(T[kk][tc4 + 0], hh.x, ll.x);
            split2(T[kk][tc4 + 1], hh.y, ll.y);
            split2(T[kk][tc4 + 2], hh.z, ll.z);
            split2(T[kk][tc4 + 3], hh.w, ll.w);
            *(ushort4*)&dh[(size_t)kk * 1024 + tc4] = hh;
            *(ushort4*)&dl[(size_t)kk * 1024 + tc4] = ll;
        }
    }
}

// ---- 64x64-tile split-bf16 MFMA NT GEMM, dbuf LDS ---------------------------
// ASTG/BSTG: operand fp32, split during staging (low re-read multiplicity only).
// KS>1: fp32 partial at Pf + z*bsC. BMODE: 0 none, 1 col-bias, 2 DC-row bias
// (+1024*b[n] where (row&127)==0; partials: only at ks==0).
template<int KS, int BMODE, bool ASTG, bool BSTG>
__global__ __launch_bounds__(256, 4) void mfma64(
    const unsigned short* __restrict__ Ah, const unsigned short* __restrict__ Al,
    const float* __restrict__ Af32, int lda, long bsA,
    const unsigned short* __restrict__ Bh, const unsigned short* __restrict__ Bl,
    const float* __restrict__ Bf32, int ldb, long bsB,
    float* __restrict__ Cf, int ldc, long bsC,
    float* __restrict__ Pf, const float* __restrict__ bias, int K)
{
    __shared__ unsigned short smem[2][8192];
    const int tid = threadIdx.x, lane = tid & 63, w = tid >> 6;
    const int wm = w >> 1, wn = w & 1;
    const int m0 = blockIdx.y * 64, n0 = blockIdx.x * 64;
    const int la = lane & 15, kg = lane >> 4;
    int bz, ks;
    if constexpr (KS > 1) { bz = blockIdx.z / KS; ks = blockIdx.z % KS; }
    else                  { bz = blockIdx.z; ks = 0; }
    const int Kc = K / KS;

    const unsigned short *pAh = nullptr, *pAl = nullptr, *pBh = nullptr, *pBl = nullptr;
    const float *pA32 = nullptr, *pB32 = nullptr;
    if constexpr (!ASTG) {
        pAh = Ah + (long)bz * bsA + (size_t)(m0 + w * 16 + la) * lda + ks * Kc + kg * 8;
        pAl = Al + (long)bz * bsA + (size_t)(m0 + w * 16 + la) * lda + ks * Kc + kg * 8;
    } else {
        pA32 = Af32 + (long)bz * bsA + (size_t)(m0 + w * 16 + la) * lda + ks * Kc + kg * 8;
    }
    if constexpr (!BSTG) {
        pBh = Bh + (long)bz * bsB + (size_t)(n0 + w * 16 + la) * ldb + ks * Kc + kg * 8;
        pBl = Bl + (long)bz * bsB + (size_t)(n0 + w * 16 + la) * ldb + ks * Kc + kg * 8;
    } else {
        pB32 = Bf32 + (long)bz * bsB + (size_t)(n0 + w * 16 + la) * ldb + ks * Kc + kg * 8;
    }

    if constexpr (!ASTG) {
        gload16(pAh, &smem[0][w * 512]); gload16(pAl, &smem[0][2048 + w * 512]);
        pAh += 32; pAl += 32;
    } else {
        float4 a0 = *(const float4*)pA32, a1 = *(const float4*)(pA32 + 4); pA32 += 32;
        splitst(a0, a1, &smem[0][w * 512 + lane * 8], &smem[0][2048 + w * 512 + lane * 8]);
    }
    if constexpr (!BSTG) {
        gload16(pBh, &smem[0][4096 + w * 512]); gload16(pBl, &smem[0][6144 + w * 512]);
        pBh += 32; pBl += 32;
    } else {
        float4 b0 = *(const float4*)pB32, b1 = *(const float4*)(pB32 + 4); pB32 += 32;
        splitst(b0, b1, &smem[0][4096 + w * 512 + lane * 8], &smem[0][6144 + w * 512 + lane * 8]);
    }
    __syncthreads();

    f32x4 acc[2][2] = {};
    int cur = 0;
    for (int kt = 0; kt < Kc; kt += 32) {
        const bool hn = (kt + 32 < Kc);
        float4 na0, na1, nb0, nb1;
        if (hn) {
            int nb = cur ^ 1;
            if constexpr (!ASTG) {
                gload16(pAh, &smem[nb][w * 512]); gload16(pAl, &smem[nb][2048 + w * 512]);
                pAh += 32; pAl += 32;
            } else {
                na0 = *(const float4*)pA32; na1 = *(const float4*)(pA32 + 4); pA32 += 32;
            }
            if constexpr (!BSTG) {
                gload16(pBh, &smem[nb][4096 + w * 512]); gload16(pBl, &smem[nb][6144 + w * 512]);
                pBh += 32; pBl += 32;
            } else {
                nb0 = *(const float4*)pB32; nb1 = *(const float4*)(pB32 + 4); pB32 += 32;
            }
        }
        bf16x8 fah[2], fal[2], fbh[2], fbl[2];
#pragma unroll
        for (int i = 0; i < 2; i++) {
            fah[i] = *reinterpret_cast<const bf16x8*>(&smem[cur][(wm * 2 + i) * 512 + lane * 8]);
            fal[i] = *reinterpret_cast<const bf16x8*>(&smem[cur][2048 + (wm * 2 + i) * 512 + lane * 8]);
            fbh[i] = *reinterpret_cast<const bf16x8*>(&smem[cur][4096 + (wn * 2 + i) * 512 + lane * 8]);
            fbl[i] = *reinterpret_cast<const bf16x8*>(&smem[cur][6144 + (wn * 2 + i) * 512 + lane * 8]);
        }
#pragma unroll
        for (int j = 0; j < 2; j++)
#pragma unroll
            for (int i = 0; i < 2; i++) {
                acc[i][j] = __builtin_amdgcn_mfma_f32_16x16x32_bf16(fah[i], fbh[j], acc[i][j], 0, 0, 0);
                acc[i][j] = __builtin_amdgcn_mfma_f32_16x16x32_bf16(fal[i], fbh[j], acc[i][j], 0, 0, 0);
                acc[i][j] = __builtin_amdgcn_mfma_f32_16x16x32_bf16(fah[i], fbl[j], acc[i][j], 0, 0, 0);
            }
        if (hn) {
            int nb = cur ^ 1;
            if constexpr (ASTG)
                splitst(na0, na1, &smem[nb][w * 512 + lane * 8], &smem[nb][2048 + w * 512 + lane * 8]);
            if constexpr (BSTG)
                splitst(nb0, nb1, &smem[nb][4096 + w * 512 + lane * 8], &smem[nb][6144 + w * 512 + lane * 8]);
        }
        __syncthreads();
        cur ^= 1;
    }

    const int r0_ = (lane >> 4) * 4, cl = lane & 15;
    if constexpr (KS > 1) {
        const int N = gridDim.x * 64;
        float* Pb = Pf + (long)blockIdx.z * bsC;
#pragma unroll
        for (int i = 0; i < 2; i++)
#pragma unroll
            for (int j = 0; j < 2; j++) {
                int gr0 = m0 + wm * 32 + i * 16 + r0_;
                int gc  = n0 + wn * 32 + j * 16 + cl;
#pragma unroll
                for (int r = 0; r < 4; r++) {
                    int gr = gr0 + r;
                    float v = acc[i][j][r];
                    if (BMODE == 2 && ks == 0 && (gr & 127) == 0)
                        v += 1024.0f * bias[gc];
                    Pb[(long)gr * N + gc] = v;
                }
            }
    } else {
        float* Cfb = Cf + (long)bz * bsC;
#pragma unroll
        for (int i = 0; i < 2; i++)
#pragma unroll
            for (int j = 0; j < 2; j++) {
                int gr0 = m0 + wm * 32 + i * 16 + r0_;
                int gc  = n0 + wn * 32 + j * 16 + cl;
                float bn = (BMODE == 1) ? bias[gc] : 0.f;
#pragma unroll
                for (int r = 0; r < 4; r++) {
                    int gr = gr0 + r;
                    float v = acc[i][j][r] + bn;
                    if (BMODE == 2 && (gr & 127) == 0) v += 1024.0f * bias[gc];
                    Cfb[(size_t)gr * ldc + gc] = v;
                }
            }
    }
}

// ---- split-K reduce -> bf16 hi/lo (GEMMs A and C) ---------------------------
template<int KS>
__global__ void reduce_k(const float* __restrict__ P,
                         unsigned short* __restrict__ Ch, unsigned short* __restrict__ Cl,
                         int mn4bits, int total4)
{
    int e = blockIdx.x * 256 + threadIdx.x;
    if (e >= total4) return;
    int bz = e >> mn4bits, rem = e & ((1 << mn4bits) - 1);
    const float4* P4 = (const float4*)P;
    float4 s = P4[((long)(bz * KS) << mn4bits) + rem];
#pragma unroll
    for (int k = 1; k < KS; k++) {
        float4 t = P4[((long)(bz * KS + k) << mn4bits) + rem];
        s.x += t.x; s.y += t.y; s.z += t.z; s.w += t.w;
    }
    long o4 = ((long)bz << mn4bits) + rem;
    ushort4 hh, ll;
    split2(s.x, hh.x, ll.x); split2(s.y, hh.y, ll.y);
    split2(s.z, hh.z, ll.z); split2(s.w, hh.w, ll.w);
    ((ushort4*)Ch)[o4] = hh;
    ((ushort4*)Cl)[o4] = ll;
}

// ---- fused scores + softmax + OVW: block per (b,h), reads P_B directly ------
__global__ __launch_bounds__(256) void score_ov(
    const float* __restrict__ P, const float* __restrict__ fq,
    const float* __restrict__ fk, const float* __restrict__ fv,
    unsigned short* __restrict__ OVWh, unsigned short* __restrict__ OVWl)
{
    int blk = blockIdx.x, tid = threadIdx.x;
    int b = blk >> 4, h = blk & 15;
    int f = tid & 63, part = tid >> 6;
    const float* base0 = P + (long)(b * 128 + 2 * f) * 3072 + h * 64 + part * 16;
    float acc = 0.f;
#pragma unroll
    for (int rr = 0; rr < 2; rr++) {
        const float* p0 = base0 + rr * 3072;
        const float* p1 = p0 + PB_STRIDE;
#pragma unroll
        for (int g = 0; g < 4; g++) {
            float4 a0 = *(const float4*)(p0 + g * 4);
            float4 a1 = *(const float4*)(p1 + g * 4);
            float4 k0 = *(const float4*)(p0 + 1024 + g * 4);
            float4 k1 = *(const float4*)(p1 + 1024 + g * 4);
            const float4 wq = *(const float4*)&fq[h * 4096 + f * 64 + part * 16 + g * 4];
            const float4 wk = *(const float4*)&fk[h * 4096 + f * 64 + part * 16 + g * 4];
            acc += wq.x * wk.x * (a0.x + a1.x) * (k0.x + k1.x)
                 + wq.y * wk.y * (a0.y + a1.y) * (k0.y + k1.y)
                 + wq.z * wk.z * (a0.z + a1.z) * (k0.z + k1.z)
                 + wq.w * wk.w * (a0.w + a1.w) * (k0.w + k1.w);
        }
    }
    __shared__ float red[256];
    __shared__ float attnL[64];
    red[tid] = acc;
    __syncthreads();
    if (tid < 64) {
        float s = red[tid] + red[tid + 64] + red[tid + 128] + red[tid + 192];
        float mx = s;
        for (int m = 1; m < 64; m <<= 1) mx = fmaxf(mx, __shfl_xor(mx, m));
        mx = fmaxf(mx, 0.0f);                   // padded zero scores join the max
        float e = expf(s - mx);
        float sum = e;
        for (int m = 1; m < 64; m <<= 1) sum += __shfl_xor(sum, m);
        sum += 960.0f * expf(-mx);              // the S-M zero-score entries
        attnL[tid] = e / sum;
    }
    __syncthreads();
    // phase 2: OVW[b][f2][h*64+d] = attn * wv * (P0+P1)v  (once-through)
#pragma unroll
    for (int it = 0; it < 8; it++) {
        int e = it * 256 + tid;                 // 2048 float4 units
        int f2 = e >> 4, c4 = e & 15;
        int d = c4 * 4;
        const float* p0 = P + (long)(b * 128 + f2) * 3072 + 2048 + h * 64 + d;
        float4 v0 = *(const float4*)p0;
        float4 v1 = *(const float4*)(p0 + PB_STRIDE);
        float a = attnL[f2 >> 1];
        const float4 wvv = *(const float4*)&fv[h * 4096 + (f2 >> 1) * 64 + d];
        ushort4 hh, ll;
        split2(a * wvv.x * (v0.x + v1.x), hh.x, ll.x);
        split2(a * wvv.y * (v0.y + v1.y), hh.y, ll.y);
        split2(a * wvv.z * (v0.z + v1.z), hh.z, ll.z);
        split2(a * wvv.w * (v0.w + v1.w), hh.w, ll.w);
        long o4 = ((long)(b * 128 + f2) * 1024 + h * 64 + d) >> 2;
        ((ushort4*)OVWh)[o4] = hh;
        ((ushort4*)OVWl)[o4] = ll;
    }
}

extern "C" void kernel_launch(void* const* d_in, const int* in_sizes, int n_in,
                              void* d_out, int out_size, void* d_ws, size_t ws_size,
                              hipStream_t stream) {
    const float* query  = (const float*)d_in[0];
    const float* w_qkv  = (const float*)d_in[1];
    const float* b_qkv  = (const float*)d_in[2];
    const float* w_out  = (const float*)d_in[3];
    const float* b_out  = (const float*)d_in[4];
    const float* freq_q = (const float*)d_in[5];
    const float* freq_k = (const float*)d_in[6];
    const float* freq_v = (const float*)d_in[7];

    char* W = (char*)d_ws;
    unsigned short* qTh   = (unsigned short*)(W);                 // [4][1024][1024]
    unsigned short* qTl   = (unsigned short*)(W + 8388608);
    unsigned short* TWFh  = (unsigned short*)(W + 16777216);      // [128][1024]
    unsigned short* TWFl  = (unsigned short*)(W + 17039360);
    unsigned short* TWIh  = (unsigned short*)(W + 17301504);      // [1024][128]
    unsigned short* TWIl  = (unsigned short*)(W + 17563648);
    unsigned short* TWQh  = (unsigned short*)(W + 17825792);      // [512][1024]
    unsigned short* TWQl  = (unsigned short*)(W + 18874368);
    unsigned short* OVWh  = (unsigned short*)(W + 19922944);      // [4][128][1024]
    unsigned short* OVWl  = (unsigned short*)(W + 20971520);
    unsigned short* POVh  = (unsigned short*)(W + 22020096);      // [4][1024][128]
    unsigned short* POVl  = (unsigned short*)(W + 23068672);
    float*          P_A   = (float*)        (W + 24133632);       // [16][2^17] floats
    float*          P_C   = (float*)        (W + 32522240);       // [16][2^17] floats
    float*          P_B   = (float*)        (W + 40910848);       // [2][2^21] floats
                                                                  // end 57688064 B

    prep<<<1280, 256, 0, stream>>>(query, qTh, qTl, TWFh, TWFl, TWIh, TWIl);

    // A: TWQ-partials  (split-K=4)
    mfma64<4, 0, false, false><<<dim3(16, 2, 16), 256, 0, stream>>>(
        TWFh, TWFl, nullptr, 1024, 0, qTh, qTl, nullptr, 1024, 1048576,
        nullptr, 0, 131072, P_A, nullptr, 1024);
    reduce_k<4><<<512, 256, 0, stream>>>(P_A, TWQh, TWQl, 15, 131072);

    // B: QF-partials[(b,f2)][c] = sum_k TWQ*w_qkv  (split-K=2, w fp32 staged;
    //    +1024*b_qkv at DC rows folded into ks==0 partial). P0+P1 == QF.
    mfma64<2, 2, false, true><<<dim3(48, 8, 2), 256, 0, stream>>>(
        TWQh, TWQl, nullptr, 1024, 0, nullptr, nullptr, w_qkv, 1024, 0,
        nullptr, 0, PB_STRIDE, P_B, b_qkv, 1024);

    // fused scores + softmax + OVW  (attn lives only in LDS)
    score_ov<<<64, 256, 0, stream>>>(P_B, freq_q, freq_k, freq_v, OVWh, OVWl);

    // C: POV-partials  (split-K=4, w_out fp32 staged on A side)
    mfma64<4, 0, true, false><<<dim3(2, 16, 16), 256, 0, stream>>>(
        nullptr, nullptr, w_out, 1024, 0, OVWh, OVWl, nullptr, 1024, 131072,
        nullptr, 0, 131072, P_C, nullptr, 1024);
    reduce_k<4><<<512, 256, 0, stream>>>(P_C, POVh, POVl, 15, 131072);

    // D: d_out[b][s][n] = sum_f2 TWI[s][f2]*POV[b][n][f2] + b_out[n]
    mfma64<1, 1, false, false><<<dim3(16, 16, 4), 256, 0, stream>>>(
        TWIh, TWIl, nullptr, 128, 0, POVh, POVl, nullptr, 128, 131072,
        (float*)d_out, 1024, 1048576, nullptr, b_out, 128);
}